// Round 1
// 77.326 us; speedup vs baseline: 1.0561x; 1.0561x over previous
//
#include <hip/hip_runtime.h>

// MultiPositiveContrastiveLoss: B=32768 problems, C=64 candidates, P=16 pos, N=48 neg.
// Wave layout: lanes 48..63 hold pos slots, lanes 0..47 hold neg slots, 4 problems/wave.
// v2: latency-restructure — all loads for the wave's 4 problems are issued up-front with
// no inter-dependencies (counts, indices, and a COALESCED lane-indexed score load; the
// candidate indirection is resolved in-wave via ds_bpermute). Inner pos-loop is a fixed
// 16-trip fully-unrolled loop using v_readlane broadcasts; invalid pos are masked with
// +1e30 (term == 0.0f exactly, so the valid-term accumulation order is bit-identical).

#define MARGIN 0.5f

constexpr int C = 64;
constexpr int P = 16;
constexpr int N = 48;
constexpr int BLOCK = 256;
constexpr int WAVES_PER_BLOCK = BLOCK / 64;      // 4
constexpr int PROBS_PER_WAVE = 4;
constexpr int PROBS_PER_BLOCK = WAVES_PER_BLOCK * PROBS_PER_WAVE;  // 16

__device__ __forceinline__ float readlane_f(float v, int l) {
    return __uint_as_float(__builtin_amdgcn_readlane(__float_as_uint(v), l));
}

__global__ __launch_bounds__(BLOCK) void mpcl_partial_kernel(
    const float* __restrict__ scores,
    const int*   __restrict__ pos_indices,
    const int*   __restrict__ neg_indices,
    const int*   __restrict__ pos_counts,
    const int*   __restrict__ neg_counts,
    float2*      __restrict__ partials,
    int B)
{
    const int lane = threadIdx.x & 63;
    const int wave = threadIdx.x >> 6;
    const int b0 = (blockIdx.x * WAVES_PER_BLOCK + wave) * PROBS_PER_WAVE;

    float tot = 0.0f;
    float cnt = 0.0f;

    if (b0 + PROBS_PER_WAVE <= B) {
        // ---- fast path: batch ALL loads, zero dependency levels between them ----
        int   pc[PROBS_PER_WAVE], nc[PROBS_PER_WAVE], idx[PROBS_PER_WAVE];
        float sc[PROBS_PER_WAVE];
        #pragma unroll
        for (int k = 0; k < PROBS_PER_WAVE; ++k) {
            const int b = b0 + k;
            pc[k] = pos_counts[b];                       // wave-uniform
            nc[k] = neg_counts[b];
            idx[k] = (lane >= 48)
                ? pos_indices[(size_t)b * P + (lane - 48)]
                : neg_indices[(size_t)b * N + lane];     // coalesced per arm
            sc[k] = scores[(size_t)b * C + lane];        // fully coalesced: C == 64
        }

        #pragma unroll
        for (int k = 0; k < PROBS_PER_WAVE; ++k) {
            // in-wave gather: candidate idx in [0,64) -> ds_bpermute
            const float val  = __shfl(sc[k], idx[k]);
            // lanes >= 48 act as permanently-invalid negs (nc <= 48)
            const float negv = (lane < nc[k]) ? val : -1e30f;
            // invalid pos -> +1e30 -> (mneg - pos_i) <= -1e29 -> relu term exactly 0.0f
            const float posv = (lane >= 48 && (lane - 48) < pc[k]) ? val : 1e30f;
            const float mneg = MARGIN + negv;

            float s = 0.0f;
            #pragma unroll
            for (int i = 0; i < P; ++i) {
                s += fmaxf(mneg - readlane_f(posv, 48 + i), 0.0f);
            }
            tot += s;
            cnt += (float)(pc[k] * nc[k]);               // closed-form pair count
        }
    } else {
        // ---- tail path (never taken for B=32768, kept for generality) ----
        for (int k = 0; k < PROBS_PER_WAVE; ++k) {
            const int b = b0 + k;
            if (b >= B) break;
            const int pc = pos_counts[b];
            const int nc = neg_counts[b];
            float myval  = 0.0f;
            float negval = -1e30f;
            if (lane >= 48) {
                const int idx = pos_indices[(size_t)b * P + (lane - 48)];
                myval = scores[(size_t)b * C + idx];
            } else if (lane < nc) {
                const int idx = neg_indices[(size_t)b * N + lane];
                negval = scores[(size_t)b * C + idx];
            }
            float s = 0.0f;
            for (int i = 0; i < pc; ++i) {
                const float pos_i = __shfl(myval, 48 + i);
                s += fmaxf(MARGIN - pos_i + negval, 0.0f);
            }
            tot += s;
            cnt += (float)(pc * nc);
        }
    }

    // wave reduce total (count is wave-uniform already)
    #pragma unroll
    for (int off = 32; off; off >>= 1) tot += __shfl_xor(tot, off);

    __shared__ float2 lds[WAVES_PER_BLOCK];
    if (lane == 0) lds[wave] = make_float2(tot, cnt);
    __syncthreads();

    if (threadIdx.x == 0) {
        float2 acc = lds[0];
        #pragma unroll
        for (int w = 1; w < WAVES_PER_BLOCK; ++w) { acc.x += lds[w].x; acc.y += lds[w].y; }
        partials[blockIdx.x] = acc;
    }
}

__global__ __launch_bounds__(BLOCK) void mpcl_final_kernel(
    const float2* __restrict__ partials, int n, float* __restrict__ out)
{
    float tot = 0.0f, cnt = 0.0f;
    for (int i = threadIdx.x; i < n; i += BLOCK) {
        const float2 p = partials[i];
        tot += p.x;
        cnt += p.y;
    }
    #pragma unroll
    for (int off = 32; off; off >>= 1) {
        tot += __shfl_xor(tot, off);
        cnt += __shfl_xor(cnt, off);
    }

    __shared__ float2 lds[WAVES_PER_BLOCK];
    const int wave = threadIdx.x >> 6;
    const int lane = threadIdx.x & 63;
    if (lane == 0) lds[wave] = make_float2(tot, cnt);
    __syncthreads();

    if (threadIdx.x == 0) {
        float T = 0.0f, Cn = 0.0f;
        #pragma unroll
        for (int w = 0; w < WAVES_PER_BLOCK; ++w) { T += lds[w].x; Cn += lds[w].y; }
        out[0] = (Cn > 0.0f) ? (T / fmaxf(Cn, 1.0f)) : 0.0f;
    }
}

extern "C" void kernel_launch(void* const* d_in, const int* in_sizes, int n_in,
                              void* d_out, int out_size, void* d_ws, size_t ws_size,
                              hipStream_t stream) {
    const float* scores      = (const float*)d_in[0];
    const int*   pos_indices = (const int*)d_in[1];
    const int*   neg_indices = (const int*)d_in[2];
    const int*   pos_counts  = (const int*)d_in[3];
    const int*   neg_counts  = (const int*)d_in[4];
    float*       out         = (float*)d_out;

    const int B = in_sizes[3];                       // 32768
    const int grid = (B + PROBS_PER_BLOCK - 1) / PROBS_PER_BLOCK;  // 2048

    float2* partials = (float2*)d_ws;                // 2048 * 8 B = 16 KB

    mpcl_partial_kernel<<<grid, BLOCK, 0, stream>>>(
        scores, pos_indices, neg_indices, pos_counts, neg_counts, partials, B);
    mpcl_final_kernel<<<1, BLOCK, 0, stream>>>(partials, grid, out);
}